// Round 2
// baseline (1007.892 us; speedup 1.0000x reference)
//
#include <hip/hip_runtime.h>
#include <hip/hip_bf16.h>
#include <math.h>

#define PI_F 3.14159265358979323846f
#define R0_F 5.0f

// ---------------------------------------------------------------------------
// Workspace layout (float):
//   P[n][816]  : per-node input projections
//       [0,48)    Pa[k][r]      = sum_c W1_a[k][r][c] * x_a[n][c]        (k=0:pa000,1:pa011,2:pa022)
//       [48,240)  Pv[k][r][i]   = sum_d W1_v[k][r][d] * x_v[n][d][i]     (k=0:pv101,1:pv110,2:pv112,3:pv121)
//       [240,816) Pd[k][r][ij]  = sum_d W1_d[k][r][d] * x_d[n][d][ij]    (k=0:pd202,1:pd211,2:pd220,3:pd222)
//   M[n][528]  : per-node accumulated messages
//       [0,48)    rank-space a messages  m_a[k][r]
//       [48,240)  rank-space v messages  m_v[k][r][c]
//       [240,528) channel-space d psi    psi_d[d][ij]
// ---------------------------------------------------------------------------

// ------------------- K1: per-node input projections ------------------------
__global__ __launch_bounds__(256) void node_proj_kernel(
    const float* __restrict__ x_a, const float* __restrict__ x_v, const float* __restrict__ x_d,
    const float* __restrict__ W1_a, const float* __restrict__ W1_v, const float* __restrict__ W1_d,
    float* __restrict__ P)
{
  int n = blockIdx.x, tid = threadIdx.x;
  __shared__ float sx[608];  // xa[128] | xv[192] | xd[288]
  {
    const size_t na = (size_t)n * 128, nv = (size_t)n * 192, nd = (size_t)n * 288;
    if (tid < 128) sx[tid] = x_a[na + tid];
    if (tid < 192) sx[128 + tid] = x_v[nv + tid];
    for (int i = tid; i < 288; i += 256) sx[320 + i] = x_d[nd + i];
  }
  __syncthreads();
  float* Pn = P + (size_t)n * 816;
  for (int o = tid; o < 816; o += 256) {
    float acc = 0.0f;
    if (o < 48) {
      int k = o >> 4, r = o & 15;
      const float* w = W1_a + k * 2048 + r * 128;
      for (int c = 0; c < 128; c++) acc += w[c] * sx[c];
    } else if (o < 240) {
      int m = o - 48; int k = m / 48, rr = m % 48, r = rr / 3, i = rr % 3;
      const float* w = W1_v + k * 1024 + r * 64;
      for (int d = 0; d < 64; d++) acc += w[d] * sx[128 + 3 * d + i];
    } else {
      int m = o - 240; int k = m / 144, rr = m % 144, r = rr / 9, ij = rr % 9;
      const float* w = W1_d + k * 512 + r * 32;
      for (int d = 0; d < 32; d++) acc += w[d] * sx[320 + 9 * d + ij];
    }
    Pn[o] = acc;
  }
}

// ------------------- K2: per-edge messages (one wave per edge) --------------
__global__ __launch_bounds__(64) void edge_kernel(
    const float* __restrict__ r_ij, const int* __restrict__ src, const int* __restrict__ dst,
    const float* __restrict__ P, float* __restrict__ M,
    const float* __restrict__ W2, const float* __restrict__ Wo_d)
{
  int e = blockIdx.x, lane = threadIdx.x;
  __shared__ float sP[816];
  __shared__ float sq[176];   // q[i][r] = sum_k W2[i][r][k]*rad[k]
  __shared__ float sT[256];   // T0[16] | T1[48] | T2[144] | T3[48]

  float r0 = r_ij[3 * (size_t)e + 0];
  float r1 = r_ij[3 * (size_t)e + 1];
  float r2 = r_ij[3 * (size_t)e + 2];
  float x_sq = (r0 * r0 + r1 * r1 + r2 * r2) * (1.0f / R0_F);
  float env = 1.0f - x_sq;
  if (env <= 0.0f) return;  // relu envelope kills every message (uniform per block)

  int s_n = src[e], d_n = dst[e];

  // rv = tens_sigmoid_vec(r * 17/5)
  float v0 = r0 * (17.0f / R0_F), v1 = r1 * (17.0f / R0_F), v2 = r2 * (17.0f / R0_F);
  float nn = sqrtf(v0 * v0 + v1 * v1 + v2 * v2);
  float sig = 2.0f / (1.0f + expf(-nn)) - 1.0f;
  float sc = sig / (nn + 1e-6f);
  float rv0 = v0 * sc, rv1 = v1 * sc, rv2 = v2 * sc;

  // radial basis
  float rad[8];
  float sqx = sqrtf(x_sq);
  #pragma unroll
  for (int k = 0; k < 8; k++) rad[k] = cosf(PI_F * (float)k * sqx) * env;

  // gather node projections (coalesced f32, L2/L3 resident)
  const float* Pn = P + (size_t)d_n * 816;
  for (int i = lane; i < 816; i += 64) sP[i] = Pn[i];

  // q[i][r], 176 values
  for (int t = lane; t < 176; t += 64) {
    int i = t >> 4, r = t & 15;
    const float* w = W2 + i * 128 + r * 8;
    float acc = 0.0f;
    #pragma unroll
    for (int k = 0; k < 8; k++) acc += w[k] * rad[k];
    sq[t] = acc;
  }
  __syncthreads();

  float* Mn = M + (size_t)s_n * 528;

  // ---- scalar messages m_a[k][r] (rank space) ----
  if (lane < 48) {
    int k = lane >> 4, r = lane & 15;
    float val;
    if (k == 0) {                       // tp_000: pa000*q0
      val = sP[r] * sq[r];
    } else if (k == 1) {                // tp_110: (pv110 . rv)*q1
      const float* pv = &sP[48 + 48 + 3 * r];
      val = (pv[0] * rv0 + pv[1] * rv1 + pv[2] * rv2) * sq[16 + r];
    } else {                            // tp_220: (pd220 : rv rv)*q2
      const float* pd = &sP[240 + 288 + 9 * r];
      float a = pd[0] * rv0 + pd[1] * rv1 + pd[2] * rv2;
      float b = pd[3] * rv0 + pd[4] * rv1 + pd[5] * rv2;
      float c = pd[6] * rv0 + pd[7] * rv1 + pd[8] * rv2;
      val = (a * rv0 + b * rv1 + c * rv2) * sq[32 + r];
    }
    atomicAdd(&Mn[lane], val);
  }

  // ---- vector messages m_v[k][r][c] (rank space), 192 values ----
  float rva[3] = {rv0, rv1, rv2};
  #pragma unroll
  for (int p = 0; p < 3; p++) {
    int t = lane + 64 * p;
    int k = t / 48, rr = t % 48, r = rr / 3, j = rr % 3;
    float val;
    if (k == 0) {                       // tp_011: pa011*q3 ⊗ rv
      val = sP[16 + r] * sq[48 + r] * rva[j];
    } else if (k == 1) {                // tp_101: pv101*q4
      val = sP[48 + 3 * r + j] * sq[64 + r];
    } else if (k == 2) {                // tp_121: (pv121 . rv)*q5 ⊗ rv
      const float* pv = &sP[48 + 144 + 3 * r];
      val = (pv[0] * rv0 + pv[1] * rv1 + pv[2] * rv2) * sq[80 + r] * rva[j];
    } else {                            // tp_211: q6 * (pd211[i,:] . rv)
      const float* pd = &sP[240 + 144 + 9 * r + 3 * j];  // j plays the role of i here
      val = sq[96 + r] * (pd[0] * rv0 + pd[1] * rv1 + pd[2] * rv2);
    }
    atomicAdd(&Mn[48 + t], val);
  }

  // ---- d-channel intermediates T (rank space) ----
  #pragma unroll
  for (int p = 0; p < 4; p++) {
    int t = lane + 64 * p;
    float val;
    if (t < 16) {                       // T0[r] = pa022*q7
      val = sP[32 + t] * sq[112 + t];
    } else if (t < 64) {                // T1[r][i] = pv112*q8
      int m = t - 16; int r = m / 3, i = m % 3;
      val = sP[48 + 96 + 3 * r + i] * sq[128 + r];
    } else if (t < 208) {               // T2[r][ij] = pd202*q9
      int m = t - 64; int r = m / 9, ij = m % 9;
      val = sP[240 + 9 * r + ij] * sq[144 + r];
    } else {                            // T3[r][i] = q10*(pd222[i,:] . rv)
      int m = t - 208; int r = m / 3, i = m % 3;
      const float* pd = &sP[240 + 432 + 9 * r + 3 * i];
      val = sq[160 + r] * (pd[0] * rv0 + pd[1] * rv1 + pd[2] * rv2);
    }
    sT[t] = val;
  }
  __syncthreads();

  // ---- psi_d[d][ij] (channel space), 288 values ----
  #pragma unroll
  for (int p = 0; p < 5; p++) {
    int t = lane + 64 * p;
    if (t >= 288) break;
    int d = t / 9, ij = t % 9, i = ij / 3, j = ij % 3;
    const float* w0 = Wo_d + d * 16;
    const float* w1 = w0 + 512;
    const float* w2 = w1 + 512;
    const float* w3 = w2 + 512;
    float a2 = 0.0f, a13 = 0.0f, a0 = 0.0f;
    #pragma unroll
    for (int r = 0; r < 16; r++) {
      a2  += w2[r] * sT[64 + 9 * r + ij];
      a13 += w1[r] * sT[16 + 3 * r + i] + w3[r] * sT[208 + 3 * r + i];
      a0  += w0[r] * sT[r];
    }
    float val = a2 + rva[j] * a13 + rva[i] * rva[j] * a0;
    atomicAdd(&Mn[240 + t], val);
  }
}

// ------------------- K3: per-node rank->channel epilogue --------------------
__global__ __launch_bounds__(256) void node_out_kernel(
    const float* __restrict__ M, const float* __restrict__ Wo_a, const float* __restrict__ Wo_v,
    float* __restrict__ out, int N)
{
  int n = blockIdx.x, tid = threadIdx.x;
  __shared__ float sM[528];
  const float* Mn = M + (size_t)n * 528;
  for (int i = tid; i < 528; i += 256) sM[i] = Mn[i];
  __syncthreads();

  const size_t baseA = 0;
  const size_t baseV = (size_t)N * 128;
  const size_t baseD = (size_t)N * 128 + (size_t)N * 192;

  for (int t = tid; t < 608; t += 256) {
    float val; size_t oidx;
    if (t < 128) {                      // B_a[c] = sum_k Wo_a[k][c][:] . m_a[k][:]
      int c = t; float acc = 0.0f;
      #pragma unroll
      for (int k = 0; k < 3; k++) {
        const float* w = Wo_a + k * 2048 + c * 16;
        const float* m = &sM[16 * k];
        #pragma unroll
        for (int r = 0; r < 16; r++) acc += w[r] * m[r];
      }
      val = acc; oidx = baseA + (size_t)n * 128 + c;
    } else if (t < 320) {               // B_v[d][j] = sum_k Wo_v[k][d][:] . m_v[k][:,j]
      int m_ = t - 128; int d = m_ / 3, j = m_ % 3; float acc = 0.0f;
      #pragma unroll
      for (int k = 0; k < 4; k++) {
        const float* w = Wo_v + k * 1024 + d * 16;
        const float* mv = &sM[48 + 48 * k];
        #pragma unroll
        for (int r = 0; r < 16; r++) acc += w[r] * mv[3 * r + j];
      }
      val = acc; oidx = baseV + (size_t)n * 192 + m_;
    } else {                            // B_d: already channel space
      int m_ = t - 320;
      val = sM[240 + m_]; oidx = baseD + (size_t)n * 288 + m_;
    }
    out[oidx] = val;
  }
}

// ---------------------------------------------------------------------------
extern "C" void kernel_launch(void* const* d_in, const int* in_sizes, int n_in,
                              void* d_out, int out_size, void* d_ws, size_t ws_size,
                              hipStream_t stream) {
  const float* r_ij = (const float*)d_in[0];
  const float* x_a  = (const float*)d_in[1];
  const float* x_v  = (const float*)d_in[2];
  const float* x_d  = (const float*)d_in[3];
  const float* W1_a = (const float*)d_in[4];
  const float* W1_v = (const float*)d_in[5];
  const float* W1_d = (const float*)d_in[6];
  const float* W2   = (const float*)d_in[7];
  const float* Wo_a = (const float*)d_in[8];
  const float* Wo_v = (const float*)d_in[9];
  const float* Wo_d = (const float*)d_in[10];
  const int*  src   = (const int*)d_in[11];
  const int*  dst   = (const int*)d_in[12];

  const int E = in_sizes[0] / 3;
  const int N = in_sizes[1] / 128;

  float* P = (float*)d_ws;
  float* M = (float*)((char*)d_ws + (size_t)N * 816 * sizeof(float));

  // M must be zeroed every call (ws is poisoned before each launch)
  hipMemsetAsync(M, 0, (size_t)N * 528 * sizeof(float), stream);

  node_proj_kernel<<<N, 256, 0, stream>>>(x_a, x_v, x_d, W1_a, W1_v, W1_d, P);
  edge_kernel<<<E, 64, 0, stream>>>(r_ij, src, dst, P, M, W2, Wo_d);
  node_out_kernel<<<N, 256, 0, stream>>>(M, Wo_a, Wo_v, (float*)d_out, N);
}